// Round 7
// baseline (43.816 us; speedup 1.0000x reference)
//
#include <hip/hip_runtime.h>

// loss = sum_{b,j} ||kps[b,j,:]||_2 * (norm > 1.0) / (B*J)
// Input: [524288, 17, 3] fp32 = 26,738,688 floats. Output: 1 fp32 scalar.
//
// Single heavy kernel (R4 main loop): grid-stride over 3072-float chunks,
// double-buffered LDS, one barrier per chunk, next chunk's wave-dense float4
// NT loads issued pre-barrier. Finalize: one fp32 atomicAdd per block into
// d_out (staggered arrival, no contention; validated in R1). d_out is zeroed
// by a 4-byte hipMemsetAsync each launch (graph-capture-safe, replaces the
// ~3us serialized 1-block reduction dispatch of R4).

#define GRID1 2048
#define BLOCK 256
#define CF4   768   // float4s per chunk = 3072 floats = 256 threads * 12 floats

typedef float vf4 __attribute__((ext_vector_type(4)));

__global__ __launch_bounds__(BLOCK) void body_loss_main(
    const vf4* __restrict__ p4, float* __restrict__ out,
    int nchunks, float inv_norm) {
    __shared__ vf4 lds[2][CF4];
    const int t = threadIdx.x;
    float acc = 0.0f;

    int c = blockIdx.x;               // always < nchunks (8704 > 2048)
    {
        const vf4* g = p4 + (size_t)c * CF4;
        vf4 r0 = __builtin_nontemporal_load(&g[t]);
        vf4 r1 = __builtin_nontemporal_load(&g[256 + t]);
        vf4 r2 = __builtin_nontemporal_load(&g[512 + t]);
        int cur = 0;
        lds[0][t] = r0; lds[0][256 + t] = r1; lds[0][512 + t] = r2;

        int next = c + GRID1;
        while (true) {
            const bool have_next = next < nchunks;
            if (have_next) {
                const vf4* gn = p4 + (size_t)next * CF4;
                r0 = __builtin_nontemporal_load(&gn[t]);
                r1 = __builtin_nontemporal_load(&gn[256 + t]);
                r2 = __builtin_nontemporal_load(&gn[512 + t]);
            }
            __syncthreads();   // lds[cur] writes (end of prev iter) visible
            const vf4 v0 = lds[cur][3 * t + 0];
            const vf4 v1 = lds[cur][3 * t + 1];
            const vf4 v2 = lds[cur][3 * t + 2];
            const float d0 = sqrtf(v0.x * v0.x + v0.y * v0.y + v0.z * v0.z);
            const float d1 = sqrtf(v0.w * v0.w + v1.x * v1.x + v1.y * v1.y);
            const float d2 = sqrtf(v1.z * v1.z + v1.w * v1.w + v2.x * v2.x);
            const float d3 = sqrtf(v2.y * v2.y + v2.z * v2.z + v2.w * v2.w);
            acc += (d0 > 1.0f ? d0 : 0.0f);
            acc += (d1 > 1.0f ? d1 : 0.0f);
            acc += (d2 > 1.0f ? d2 : 0.0f);
            acc += (d3 > 1.0f ? d3 : 0.0f);
            if (!have_next) break;
            // lds[cur^1]'s readers finished before this iteration's barrier.
            cur ^= 1;
            lds[cur][t] = r0; lds[cur][256 + t] = r1; lds[cur][512 + t] = r2;
            next += GRID1;
        }
    }

    // 64-lane butterfly reduce, then combine 4 waves, one atomic per block.
    #pragma unroll
    for (int off = 32; off > 0; off >>= 1)
        acc += __shfl_down(acc, off, 64);

    __shared__ float wsum[4];
    const int lane = t & 63, wid = t >> 6;
    if (lane == 0) wsum[wid] = acc;
    __syncthreads();
    if (t == 0)
        atomicAdd(out, (wsum[0] + wsum[1] + wsum[2] + wsum[3]) * inv_norm);
}

extern "C" void kernel_launch(void* const* d_in, const int* in_sizes, int n_in,
                              void* d_out, int out_size, void* d_ws, size_t ws_size,
                              hipStream_t stream) {
    const float* in = (const float*)d_in[0];
    float* out = (float*)d_out;

    const long long nfloats  = in_sizes[0];               // 26,738,688
    const long long ntriples = nfloats / 3;               // 8,912,896
    const int nchunks = (int)(nfloats / (CF4 * 4));       // 8704 exact
    const float inv_norm = 1.0f / (float)ntriples;

    // d_out poisoned once before timing, never re-zeroed between replays:
    // zero it ourselves every launch (4-byte async fill, graph-capture-safe).
    hipMemsetAsync(out, 0, sizeof(float), stream);

    body_loss_main<<<GRID1, BLOCK, 0, stream>>>(
        (const vf4*)in, out, nchunks, inv_norm);
}

// Round 8
// 22.168 us; speedup vs baseline: 1.9766x; 1.9766x over previous
//
#include <hip/hip_runtime.h>

// loss = sum_{b,j} ||kps[b,j,:]||_2 * (norm > 1.0) / (B*J)
// Input: [524288, 17, 3] fp32 = 26,738,688 floats. Output: 1 fp32 scalar.
//
// Kernel 1: 2176 blocks x exactly 4 chunks of 3072 floats, fully unrolled
// 4-phase pipeline, 2-deep NT-load prefetch, double-buffered LDS, one
// barrier per phase. Partials -> d_ws (plain stores, no atomics/fences).
// Kernel 2: 1 block reduces 2176 partials -> d_out.
// NO hipMemsetAsync anywhere: in-graph tiny fills cost ~22 us (R7 lesson).

#define GRID1 2176
#define BLOCK 256
#define CF4   768   // float4s per chunk = 3072 floats

typedef float vf4 __attribute__((ext_vector_type(4)));

__device__ __forceinline__ void load_chunk(const vf4* __restrict__ p4,
                                           int chunk, int t,
                                           vf4& r0, vf4& r1, vf4& r2) {
    const vf4* g = p4 + (size_t)chunk * CF4;
    r0 = __builtin_nontemporal_load(&g[t]);
    r1 = __builtin_nontemporal_load(&g[256 + t]);
    r2 = __builtin_nontemporal_load(&g[512 + t]);
}

__global__ __launch_bounds__(BLOCK) void body_loss_main(
    const vf4* __restrict__ p4, float* __restrict__ partial) {
    __shared__ vf4 lds[2][CF4];
    const int t = threadIdx.x;
    float acc = 0.0f;

    const int c = blockIdx.x;           // chunks: c, c+GRID1, c+2*GRID1, c+3*GRID1

    vf4 a0, a1, a2, b0, b1, b2;
    // Prologue: phase-0 data -> LDS0; phase-1 data in regs.
    load_chunk(p4, c, t, a0, a1, a2);
    load_chunk(p4, c + GRID1, t, b0, b1, b2);
    lds[0][t] = a0; lds[0][256 + t] = a1; lds[0][512 + t] = a2;
    __syncthreads();

    #pragma unroll
    for (int ph = 0; ph < 4; ++ph) {
        const int cur = ph & 1;
        // Prefetch phase ph+2 (2-deep).
        if (ph < 2)
            load_chunk(p4, c + (ph + 2) * GRID1, t, a0, a1, a2);
        // Consume current LDS buffer.
        const vf4 v0 = lds[cur][3 * t + 0];
        const vf4 v1 = lds[cur][3 * t + 1];
        const vf4 v2 = lds[cur][3 * t + 2];
        const float d0 = sqrtf(v0.x * v0.x + v0.y * v0.y + v0.z * v0.z);
        const float d1 = sqrtf(v0.w * v0.w + v1.x * v1.x + v1.y * v1.y);
        const float d2 = sqrtf(v1.z * v1.z + v1.w * v1.w + v2.x * v2.x);
        const float d3 = sqrtf(v2.y * v2.y + v2.z * v2.z + v2.w * v2.w);
        acc += (d0 > 1.0f ? d0 : 0.0f);
        acc += (d1 > 1.0f ? d1 : 0.0f);
        acc += (d2 > 1.0f ? d2 : 0.0f);
        acc += (d3 > 1.0f ? d3 : 0.0f);
        if (ph < 3) {
            // Stage next phase's registers into the other buffer.
            // (Safe: every wave's reads of that buffer completed before the
            //  barrier it crossed to get here — lgkmcnt consumption order.)
            const int nxt = cur ^ 1;
            lds[nxt][t] = b0; lds[nxt][256 + t] = b1; lds[nxt][512 + t] = b2;
            b0 = a0; b1 = a1; b2 = a2;
            __syncthreads();
        }
    }

    // 64-lane butterfly reduce, then combine the 4 waves.
    #pragma unroll
    for (int off = 32; off > 0; off >>= 1)
        acc += __shfl_down(acc, off, 64);

    __shared__ float wsum[4];
    const int lane = t & 63, wid = t >> 6;
    if (lane == 0) wsum[wid] = acc;
    __syncthreads();
    if (t == 0)
        partial[blockIdx.x] = wsum[0] + wsum[1] + wsum[2] + wsum[3];
}

__global__ __launch_bounds__(BLOCK) void body_loss_final(
    const float* __restrict__ partial, float* __restrict__ out, float inv_norm) {
    const int t = threadIdx.x;
    float s = 0.0f;
    #pragma unroll
    for (int k = 0; k < 9; ++k) {            // ceil(2176/256) = 9
        const int i = k * BLOCK + t;
        if (i < GRID1) s += partial[i];
    }
    #pragma unroll
    for (int off = 32; off > 0; off >>= 1)
        s += __shfl_down(s, off, 64);
    __shared__ float wsum[4];
    const int lane = t & 63, wid = t >> 6;
    if (lane == 0) wsum[wid] = s;
    __syncthreads();
    if (t == 0)
        out[0] = (wsum[0] + wsum[1] + wsum[2] + wsum[3]) * inv_norm;
}

extern "C" void kernel_launch(void* const* d_in, const int* in_sizes, int n_in,
                              void* d_out, int out_size, void* d_ws, size_t ws_size,
                              hipStream_t stream) {
    const float* in = (const float*)d_in[0];
    float* out = (float*)d_out;
    float* partial = (float*)d_ws;   // 2176 floats scratch

    const long long nfloats  = in_sizes[0];        // 26,738,688 = 8704 * 3072
    const long long ntriples = nfloats / 3;        // 8,912,896
    const float inv_norm = 1.0f / (float)ntriples;

    body_loss_main<<<GRID1, BLOCK, 0, stream>>>((const vf4*)in, partial);
    body_loss_final<<<1, BLOCK, 0, stream>>>(partial, out, inv_norm);
}